// Round 10
// baseline (435.737 us; speedup 1.0000x reference)
//
#include <hip/hip_runtime.h>

#define NN 20000
#define NE 640000
#define HD 128
#define NL 3
#define NG 128
#define NC 2
#define BN_EPS 1e-5f

typedef __attribute__((ext_vector_type(4))) float f32x4;
typedef __attribute__((ext_vector_type(8))) _Float16 f16x8;

// ---------- fused setup: weight fp16-split prep + encoder + dst histogram ----------
// W = Whi + Wlo/1024, both fp16 (Wlo pre-scaled so residual is fp16-normal).
// blocks [0,48): prep; [48,1298): enc (fp16 out); [1298,3798): hist
__global__ void k_setup(const float* __restrict__ x, const float* __restrict__ encW,
                        const float* __restrict__ encb,
                        const float* __restrict__ W1, const float* __restrict__ W2,
                        const int* __restrict__ ei,
                        _Float16* __restrict__ Wt,
                        _Float16* __restrict__ h,
                        int* __restrict__ counts) {
    int b = blockIdx.x, tid = threadIdx.x;
    if (b < 48) {
        int t = b * 256 + tid;                 // 6*2048 = 12288
        if (t >= 6 * 2048) return;
        int mat = t >> 11;
        int rem = t & 2047;
        int n  = rem >> 4;
        int k0 = (rem & 15) * 8;
        int l  = mat >> 1;
        const float* src = (mat & 1) ? (W2 + l * HD * HD) : (W1 + l * HD * HD);
        _Float16* dhi = Wt + mat * HD * HD;
        _Float16* dlo = Wt + (6 + mat) * HD * HD;
        f16x8 hi, lo;
#pragma unroll
        for (int j = 0; j < 8; j++) {
            float w = src[(k0 + j) * HD + n];
            _Float16 hh = (_Float16)w;
            hi[j] = hh;
            lo[j] = (_Float16)((w - (float)hh) * 1024.0f);
        }
        *(f16x8*)&dhi[n * HD + k0] = hi;
        *(f16x8*)&dlo[n * HD + k0] = lo;
    } else if (b < 48 + 1250) {
        int i = (b - 48) * 256 + tid;          // NN*16
        if (i >= NN * 16) return;
        int n  = i >> 4;
        int c8 = (i & 15) * 8;
        float xv = x[n];
        f16x8 o;
#pragma unroll
        for (int j = 0; j < 8; j++)
            o[j] = (_Float16)fmaf(xv, encW[c8 + j], encb[c8 + j]);
        *(f16x8*)&h[n * HD + c8] = o;
    } else {
        int e = (b - 1298) * 256 + tid;        // NE
        if (e >= NE) return;
        atomicAdd(&counts[ei[NE + e]], 1);
    }
}

// ---------- CSR scan ----------
__global__ __launch_bounds__(1024) void k_scan(const int* __restrict__ counts,
                                               int* __restrict__ row_ptr,
                                               int* __restrict__ cursor) {
    __shared__ int sdata[1024];
    int tid = threadIdx.x;
    int base = tid * 20;
    int loc[20];
    int run = 0;
#pragma unroll
    for (int j = 0; j < 20; j++) {
        int i = base + j;
        int v = (i < NN) ? counts[i] : 0;
        loc[j] = run;
        run += v;
    }
    sdata[tid] = run;
    __syncthreads();
    for (int off = 1; off < 1024; off <<= 1) {
        int t = (tid >= off) ? sdata[tid - off] : 0;
        __syncthreads();
        sdata[tid] += t;
        __syncthreads();
    }
    int excl = sdata[tid] - run;
#pragma unroll
    for (int j = 0; j < 20; j++) {
        int i = base + j;
        if (i < NN) {
            int o = excl + loc[j];
            row_ptr[i] = o;
            cursor[i]  = o;
        }
    }
    if (tid == 1023) row_ptr[NN] = NE;
}

__global__ void k_fill(const int* __restrict__ ei, int* __restrict__ cursor,
                       int* __restrict__ csr_src) {
    int e = blockIdx.x * blockDim.x + threadIdx.x;
    if (e >= NE) return;
    int pos = atomicAdd(&cursor[ei[NE + e]], 1);
    csr_src[pos] = ei[e];
}

// ---------- fused [gather-aggregate +] fp16-MFMA GEMM ----------
// GATHER: A-tile rows are built by CSR gather-aggregation of u
//         (z[n] = (1+eps)*f(u[n]) + sum f(u[s]), f = inline BN+ReLU if APPLY).
// !GATHER: A-tile staged directly from A (with f applied if APPLY).
// GEMM: out = Atile @ (Whi + Wlo/1024)^T, fp16 MFMA, fp32 accumulate.
// 64 rows x 128 cols per block, 4 waves each own a 32-col strip.
// MFMA 16x16x32 f16: A[m=lane&15][k=quad*8+j]; C/D col=lane&15, row=quad*4+reg.
#define AST 136
template <bool GATHER, bool APPLY>
__global__ __launch_bounds__(256) void k_mm(
    const _Float16* __restrict__ A,            // GATHER ? u (gathered) : direct input
    const int* __restrict__ row_ptr, const int* __restrict__ csr_src,
    const float* __restrict__ eps_gin, int l,
    const _Float16* __restrict__ Whi, const _Float16* __restrict__ Wlo,
    const float* __restrict__ pcolsum, const float* __restrict__ pcolsq,
    const float* __restrict__ gamma, const float* __restrict__ beta,
    _Float16* __restrict__ out,
    float* __restrict__ colsum, float* __restrict__ colsq) {
    __shared__ __align__(16) _Float16 As[64 * AST];
    int tid  = threadIdx.x;
    int wave = tid >> 6, lane = tid & 63;
    int quad = lane >> 4, l16 = lane & 15;
    int r0   = blockIdx.x * 64;
    int n0w  = wave * 32;

    // B fragments (fp16 weights), once per block
    f16x8 bhi[2][4], blo[2][4];
#pragma unroll
    for (int nt = 0; nt < 2; nt++) {
        int n = n0w + nt * 16 + l16;
#pragma unroll
        for (int kq = 0; kq < 4; kq++) {
            int k = kq * 32 + quad * 8;
            bhi[nt][kq] = *(const f16x8*)&Whi[n * HD + k];
            blo[nt][kq] = *(const f16x8*)&Wlo[n * HD + k];
        }
    }

    // ---- stage A-tile (64 x 128 fp16) ----
    {
        int c8 = (tid & 15) * 8;               // channel chunk
        int nl = tid >> 4;                     // node lane 0..15
        float sc[8], sh[8];
        if (APPLY) {
#pragma unroll
            for (int j = 0; j < 8; j++) {
                float mu  = pcolsum[c8 + j] * (1.0f / NN);
                float var = pcolsq[c8 + j] * (1.0f / NN) - mu * mu;
                float a = gamma[c8 + j] * rsqrtf(var + BN_EPS);
                sc[j] = a;
                sh[j] = beta[c8 + j] - a * mu;
            }
        }
        float e = GATHER ? (1.0f + eps_gin[l]) : 0.f;
#pragma unroll
        for (int r = 0; r < 4; r++) {
            int rloc = r * 16 + nl;
            int row = r0 + rloc;
            f16x8 o = (f16x8)(_Float16)0.f;
            if (GATHER) {
                float acc[8] = { 0, 0, 0, 0, 0, 0, 0, 0 };
                if (row < NN) {
                    f16x8 s = *(const f16x8*)&A[row * HD + c8];
#pragma unroll
                    for (int j = 0; j < 8; j++) {
                        float v = (float)s[j];
                        if (APPLY) v = fmaxf(fmaf(sc[j], v, sh[j]), 0.f);
                        acc[j] = e * v;
                    }
                    int p = row_ptr[row], end = row_ptr[row + 1];
                    for (; p + 7 < end; p += 8) {
                        f16x8 rr[8];
#pragma unroll
                        for (int j = 0; j < 8; j++)
                            rr[j] = *(const f16x8*)&A[csr_src[p + j] * HD + c8];
#pragma unroll
                        for (int j = 0; j < 8; j++)
#pragma unroll
                            for (int q = 0; q < 8; q++) {
                                float v = (float)rr[j][q];
                                if (APPLY) v = fmaxf(fmaf(sc[q], v, sh[q]), 0.f);
                                acc[q] += v;
                            }
                    }
                    for (; p < end; p++) {
                        f16x8 rr = *(const f16x8*)&A[csr_src[p] * HD + c8];
#pragma unroll
                        for (int q = 0; q < 8; q++) {
                            float v = (float)rr[q];
                            if (APPLY) v = fmaxf(fmaf(sc[q], v, sh[q]), 0.f);
                            acc[q] += v;
                        }
                    }
                }
#pragma unroll
                for (int j = 0; j < 8; j++) o[j] = (_Float16)acc[j];
            } else {
                if (row < NN) {
                    f16x8 v = *(const f16x8*)&A[row * HD + c8];
                    if (APPLY) {
#pragma unroll
                        for (int j = 0; j < 8; j++)
                            o[j] = (_Float16)fmaxf(fmaf(sc[j], (float)v[j], sh[j]), 0.f);
                    } else {
                        o = v;
                    }
                }
            }
            *(f16x8*)&As[rloc * AST + c8] = o;
        }
    }
    __syncthreads();

    f32x4 ach[4][2], acl[4][2];
#pragma unroll
    for (int mt = 0; mt < 4; mt++)
#pragma unroll
        for (int nt = 0; nt < 2; nt++)
#pragma unroll
            for (int e2 = 0; e2 < 4; e2++) { ach[mt][nt][e2] = 0.f; acl[mt][nt][e2] = 0.f; }

#pragma unroll
    for (int mt = 0; mt < 4; mt++) {
        int mrow = mt * 16 + l16;
#pragma unroll
        for (int kq = 0; kq < 4; kq++) {
            f16x8 a = *(const f16x8*)&As[mrow * AST + kq * 32 + quad * 8];
#pragma unroll
            for (int nt = 0; nt < 2; nt++) {
                ach[mt][nt] = __builtin_amdgcn_mfma_f32_16x16x32_f16(
                    a, bhi[nt][kq], ach[mt][nt], 0, 0, 0);
                acl[mt][nt] = __builtin_amdgcn_mfma_f32_16x16x32_f16(
                    a, blo[nt][kq], acl[mt][nt], 0, 0, 0);
            }
        }
    }

    float s[2] = { 0.f, 0.f }, q[2] = { 0.f, 0.f };
#pragma unroll
    for (int mt = 0; mt < 4; mt++) {
        int rbase = r0 + mt * 16 + quad * 4;
#pragma unroll
        for (int rr = 0; rr < 4; rr++) {
            int row = rbase + rr;
            if (row < NN) {
#pragma unroll
                for (int nt = 0; nt < 2; nt++) {
                    float v = fmaf(acl[mt][nt][rr], 1.0f / 1024.0f, ach[mt][nt][rr]);
                    out[row * HD + n0w + nt * 16 + l16] = (_Float16)v;
                    s[nt] += v;
                    q[nt] = fmaf(v, v, q[nt]);
                }
            }
        }
    }
#pragma unroll
    for (int nt = 0; nt < 2; nt++) {
        float ss = s[nt], qq = q[nt];
        ss += __shfl_xor(ss, 16); ss += __shfl_xor(ss, 32);
        qq += __shfl_xor(qq, 16); qq += __shfl_xor(qq, 32);
        if (lane < 16) {
            atomicAdd(&colsum[n0w + nt * 16 + lane], ss);
            atomicAdd(&colsq[n0w + nt * 16 + lane], qq);
        }
    }
}

// ---------- pool + classifier (fp16 u, inline BN) ----------
__global__ __launch_bounds__(256) void k_pool(
    const _Float16* __restrict__ u,
    const float* __restrict__ pcolsum, const float* __restrict__ pcolsq,
    const float* __restrict__ gamma, const float* __restrict__ beta,
    const int* __restrict__ batch, const float* __restrict__ Wc,
    const float* __restrict__ bc, float* __restrict__ out) {
    __shared__ float part[2][HD];
    __shared__ float pooled[HD];
    __shared__ int range[2];
    int g = blockIdx.x;
    int tid = threadIdx.x;
    if (tid < 2) {
        int target = g + tid;
        int lo = 0, hi = NN;
        while (lo < hi) {
            int mid = (lo + hi) >> 1;
            if (batch[mid] < target) lo = mid + 1; else hi = mid;
        }
        range[tid] = lo;
    }
    __syncthreads();
    int start = range[0], end = range[1];
    int c    = tid & (HD - 1);
    int half = tid >> 7;
    float mu  = pcolsum[c] * (1.0f / NN);
    float var = pcolsq[c] * (1.0f / NN) - mu * mu;
    float sc = gamma[c] * rsqrtf(var + BN_EPS);
    float sh = beta[c] - sc * mu;
    float acc = 0.f;
    for (int n = start + half; n < end; n += 2)
        acc += fmaxf(fmaf(sc, (float)u[n * HD + c], sh), 0.f);
    part[half][c] = acc;
    __syncthreads();
    if (tid < HD) {
        float inv = 1.0f / fmaxf((float)(end - start), 1.0f);
        pooled[tid] = (part[0][tid] + part[1][tid]) * inv;
    }
    __syncthreads();
    if (tid < NC) {
        float a = bc[tid];
        for (int k = 0; k < HD; k++)
            a = fmaf(pooled[k], Wc[k * NC + tid], a);
        out[g * NC + tid] = a;
    }
}

extern "C" void kernel_launch(void* const* d_in, const int* in_sizes, int n_in,
                              void* d_out, int out_size, void* d_ws, size_t ws_size,
                              hipStream_t stream) {
    const float* x      = (const float*)d_in[0];
    const int*   ei     = (const int*)d_in[1];
    const int*   batch  = (const int*)d_in[2];
    const float* enc_W  = (const float*)d_in[3];
    const float* enc_b  = (const float*)d_in[4];
    const float* W1     = (const float*)d_in[5];
    // d_in[6] = b1, d_in[10] = b2: cancel in the following BN (mean shift)
    const float* g1     = (const float*)d_in[7];
    const float* be1    = (const float*)d_in[8];
    const float* W2     = (const float*)d_in[9];
    const float* eps_g  = (const float*)d_in[11];
    const float* bn_g   = (const float*)d_in[12];
    const float* bn_b   = (const float*)d_in[13];
    const float* cls_W  = (const float*)d_in[14];
    const float* cls_b  = (const float*)d_in[15];
    float* out = (float*)d_out;

    _Float16* Wt   = (_Float16*)d_ws;                  // 12 x HD x HD fp16 (hi:0-5, lo:6-11)
    _Float16* bufT = Wt + 12 * HD * HD;                // NN*HD fp16 (gemm1 out)
    _Float16* bufU = bufT + NN * HD;                   // NN*HD fp16 (gathered tensor)
    float* stats  = (float*)(bufU + NN * HD);          // 6 x 256 f32
    int* counts   = (int*)(stats + 6 * 256);           // NN (also cursor)
    int* row_ptr  = counts + NN;                       // NN+1
    int* csr_src  = row_ptr + NN + 1;                  // NE

    hipMemsetAsync(stats, 0, (6 * 256 + NN) * sizeof(int), stream);

    dim3 b256(256);
    k_setup<<<3798, b256, 0, stream>>>(x, enc_W, enc_b, W1, W2, ei, Wt, bufU, counts);
    k_scan<<<1, 1024, 0, stream>>>(counts, row_ptr, counts /*cursor*/);
    k_fill<<<(NE + 255) / 256, b256, 0, stream>>>(ei, counts, csr_src);

    const int gemm_blocks = (NN + 63) / 64;          // 313

    for (int l = 0; l < NL; l++) {
        float* st1 = stats + (2 * l) * 256;       // t stats
        float* st2 = stats + (2 * l + 1) * 256;   // u stats
        _Float16* Whi1 = Wt + (2 * l) * HD * HD;
        _Float16* Wlo1 = Wt + (6 + 2 * l) * HD * HD;
        _Float16* Whi2 = Wt + (2 * l + 1) * HD * HD;
        _Float16* Wlo2 = Wt + (6 + 2 * l + 1) * HD * HD;
        if (l == 0) {
            k_mm<true, false><<<gemm_blocks, b256, 0, stream>>>(
                bufU, row_ptr, csr_src, eps_g, l, Whi1, Wlo1,
                nullptr, nullptr, nullptr, nullptr, bufT, st1, st1 + 128);
        } else {
            float* stp = stats + (2 * (l - 1) + 1) * 256;
            k_mm<true, true><<<gemm_blocks, b256, 0, stream>>>(
                bufU, row_ptr, csr_src, eps_g, l, Whi1, Wlo1,
                stp, stp + 128, bn_g + (l - 1) * HD, bn_b + (l - 1) * HD,
                bufT, st1, st1 + 128);
        }
        k_mm<false, true><<<gemm_blocks, b256, 0, stream>>>(
            bufT, nullptr, nullptr, nullptr, 0, Whi2, Wlo2,
            st1, st1 + 128, g1 + l * HD, be1 + l * HD, bufU, st2, st2 + 128);
    }
    float* st5 = stats + 5 * 256;
    k_pool<<<NG, b256, 0, stream>>>(bufU, st5, st5 + 128,
                                    bn_g + 2 * HD, bn_b + 2 * HD,
                                    batch, cls_W, cls_b, out);
}

// Round 11
// 361.787 us; speedup vs baseline: 1.2044x; 1.2044x over previous
//
#include <hip/hip_runtime.h>

#define NN 20000
#define NE 640000
#define HD 128
#define NL 3
#define NG 128
#define NC 2
#define BN_EPS 1e-5f

typedef __attribute__((ext_vector_type(4))) float f32x4;
typedef __attribute__((ext_vector_type(8))) _Float16 f16x8;

// ---------- fused setup: weight fp16-split prep + encoder + dst histogram ----------
// W = Whi + Wlo/1024, both fp16 (Wlo pre-scaled so residual is fp16-normal).
// blocks [0,48): prep; [48,1298): enc (fp16 out); [1298,3798): hist
__global__ void k_setup(const float* __restrict__ x, const float* __restrict__ encW,
                        const float* __restrict__ encb,
                        const float* __restrict__ W1, const float* __restrict__ W2,
                        const int* __restrict__ ei,
                        _Float16* __restrict__ Wt,
                        _Float16* __restrict__ h,
                        int* __restrict__ counts) {
    int b = blockIdx.x, tid = threadIdx.x;
    if (b < 48) {
        int t = b * 256 + tid;                 // 6*2048 = 12288
        if (t >= 6 * 2048) return;
        int mat = t >> 11;
        int rem = t & 2047;
        int n  = rem >> 4;
        int k0 = (rem & 15) * 8;
        int l  = mat >> 1;
        const float* src = (mat & 1) ? (W2 + l * HD * HD) : (W1 + l * HD * HD);
        _Float16* dhi = Wt + mat * HD * HD;
        _Float16* dlo = Wt + (6 + mat) * HD * HD;
        f16x8 hi, lo;
#pragma unroll
        for (int j = 0; j < 8; j++) {
            float w = src[(k0 + j) * HD + n];
            _Float16 hh = (_Float16)w;
            hi[j] = hh;
            lo[j] = (_Float16)((w - (float)hh) * 1024.0f);
        }
        *(f16x8*)&dhi[n * HD + k0] = hi;
        *(f16x8*)&dlo[n * HD + k0] = lo;
    } else if (b < 48 + 1250) {
        int i = (b - 48) * 256 + tid;          // NN*16
        if (i >= NN * 16) return;
        int n  = i >> 4;
        int c8 = (i & 15) * 8;
        float xv = x[n];
        f16x8 o;
#pragma unroll
        for (int j = 0; j < 8; j++)
            o[j] = (_Float16)fmaf(xv, encW[c8 + j], encb[c8 + j]);
        *(f16x8*)&h[n * HD + c8] = o;
    } else {
        int e = (b - 1298) * 256 + tid;        // NE
        if (e >= NE) return;
        atomicAdd(&counts[ei[NE + e]], 1);
    }
}

// ---------- CSR scan ----------
__global__ __launch_bounds__(1024) void k_scan(const int* __restrict__ counts,
                                               int* __restrict__ row_ptr,
                                               int* __restrict__ cursor) {
    __shared__ int sdata[1024];
    int tid = threadIdx.x;
    int base = tid * 20;
    int loc[20];
    int run = 0;
#pragma unroll
    for (int j = 0; j < 20; j++) {
        int i = base + j;
        int v = (i < NN) ? counts[i] : 0;
        loc[j] = run;
        run += v;
    }
    sdata[tid] = run;
    __syncthreads();
    for (int off = 1; off < 1024; off <<= 1) {
        int t = (tid >= off) ? sdata[tid - off] : 0;
        __syncthreads();
        sdata[tid] += t;
        __syncthreads();
    }
    int excl = sdata[tid] - run;
#pragma unroll
    for (int j = 0; j < 20; j++) {
        int i = base + j;
        if (i < NN) {
            int o = excl + loc[j];
            row_ptr[i] = o;
            cursor[i]  = o;
        }
    }
    if (tid == 1023) row_ptr[NN] = NE;
}

__global__ void k_fill(const int* __restrict__ ei, int* __restrict__ cursor,
                       int* __restrict__ csr_src) {
    int e = blockIdx.x * blockDim.x + threadIdx.x;
    if (e >= NE) return;
    int pos = atomicAdd(&cursor[ei[NE + e]], 1);
    csr_src[pos] = ei[e];
}

// ---------- aggregation: fp16 gather, fp32 accumulate, fp16 out ----------
// 1250 blocks: one (node, c8) pair per thread — parallelism hides gather latency.
// APPLY: f(v) = relu(sc*v+sh), BN params computed inline from stats.
template <bool APPLY>
__global__ void k_aggr(const int* __restrict__ row_ptr, const int* __restrict__ csr_src,
                       const _Float16* __restrict__ u,
                       const float* __restrict__ pcolsum, const float* __restrict__ pcolsq,
                       const float* __restrict__ gamma, const float* __restrict__ beta,
                       const float* __restrict__ eps_gin, int l,
                       _Float16* __restrict__ z) {
    int i = blockIdx.x * blockDim.x + threadIdx.x;   // NN*16
    if (i >= NN * 16) return;
    int n  = i >> 4;
    int c8 = (i & 15) * 8;
    float e = 1.0f + eps_gin[l];
    float sc[8], sh[8];
    if (APPLY) {
#pragma unroll
        for (int j = 0; j < 8; j++) {
            float mu  = pcolsum[c8 + j] * (1.0f / NN);
            float var = pcolsq[c8 + j] * (1.0f / NN) - mu * mu;
            float a = gamma[c8 + j] * rsqrtf(var + BN_EPS);
            sc[j] = a;
            sh[j] = beta[c8 + j] - a * mu;
        }
    }
    float acc[8];
    {
        f16x8 r = *(const f16x8*)&u[n * HD + c8];
#pragma unroll
        for (int j = 0; j < 8; j++) {
            float v = (float)r[j];
            if (APPLY) v = fmaxf(fmaf(sc[j], v, sh[j]), 0.f);
            acc[j] = e * v;
        }
    }
    int p = row_ptr[n], end = row_ptr[n + 1];
    for (; p + 7 < end; p += 8) {
        f16x8 r[8];
#pragma unroll
        for (int j = 0; j < 8; j++) r[j] = *(const f16x8*)&u[csr_src[p + j] * HD + c8];
#pragma unroll
        for (int j = 0; j < 8; j++)
#pragma unroll
            for (int q = 0; q < 8; q++) {
                float v = (float)r[j][q];
                if (APPLY) v = fmaxf(fmaf(sc[q], v, sh[q]), 0.f);
                acc[q] += v;
            }
    }
    for (; p < end; p++) {
        f16x8 r = *(const f16x8*)&u[csr_src[p] * HD + c8];
#pragma unroll
        for (int q = 0; q < 8; q++) {
            float v = (float)r[q];
            if (APPLY) v = fmaxf(fmaf(sc[q], v, sh[q]), 0.f);
            acc[q] += v;
        }
    }
    f16x8 o;
#pragma unroll
    for (int j = 0; j < 8; j++) o[j] = (_Float16)acc[j];
    *(f16x8*)&z[n * HD + c8] = o;
}

// ---------- fp16-MFMA GEMM with scaled weight split, LDS-staged A ----------
// out = f(A_f16) @ (Whi + Wlo/1024)^T; A is exact in fp16 (no A split).
// 64 rows x 128 cols per block, 4 waves each own a 32-col strip.
// MFMA 16x16x32 f16: A[m=lane&15][k=quad*8+j]; C/D col=lane&15, row=quad*4+reg.
#define AST 136
template <bool BNRELU>
__global__ __launch_bounds__(256) void k_gemm(
    const _Float16* __restrict__ A,
    const _Float16* __restrict__ Whi, const _Float16* __restrict__ Wlo,
    const float* __restrict__ pcolsum, const float* __restrict__ pcolsq,
    const float* __restrict__ gamma, const float* __restrict__ beta,
    _Float16* __restrict__ out,
    float* __restrict__ colsum, float* __restrict__ colsq) {
    __shared__ __align__(16) _Float16 As[64 * AST];
    int tid  = threadIdx.x;
    int wave = tid >> 6, lane = tid & 63;
    int quad = lane >> 4, l16 = lane & 15;
    int r0   = blockIdx.x * 64;
    int n0w  = wave * 32;

    f16x8 bhi[2][4], blo[2][4];
#pragma unroll
    for (int nt = 0; nt < 2; nt++) {
        int n = n0w + nt * 16 + l16;
#pragma unroll
        for (int kq = 0; kq < 4; kq++) {
            int k = kq * 32 + quad * 8;
            bhi[nt][kq] = *(const f16x8*)&Whi[n * HD + k];
            blo[nt][kq] = *(const f16x8*)&Wlo[n * HD + k];
        }
    }

    // stage A: 64 rows x 128 ch fp16, 16 B/thread/iter, 4 iters, coalesced
    {
        int c8 = (tid & 15) * 8;
        int nl = tid >> 4;                    // 0..15
        float sc[8], sh[8];
        if (BNRELU) {
#pragma unroll
            for (int j = 0; j < 8; j++) {
                float mu  = pcolsum[c8 + j] * (1.0f / NN);
                float var = pcolsq[c8 + j] * (1.0f / NN) - mu * mu;
                float a = gamma[c8 + j] * rsqrtf(var + BN_EPS);
                sc[j] = a;
                sh[j] = beta[c8 + j] - a * mu;
            }
        }
#pragma unroll
        for (int i = 0; i < 4; i++) {
            int r = i * 16 + nl;
            int row = r0 + r;
            f16x8 o = (f16x8)(_Float16)0.f;
            if (row < NN) {
                f16x8 v = *(const f16x8*)&A[row * HD + c8];
                if (BNRELU) {
#pragma unroll
                    for (int j = 0; j < 8; j++)
                        o[j] = (_Float16)fmaxf(fmaf(sc[j], (float)v[j], sh[j]), 0.f);
                } else {
                    o = v;
                }
            }
            *(f16x8*)&As[r * AST + c8] = o;
        }
    }
    __syncthreads();

    f32x4 ach[4][2], acl[4][2];
#pragma unroll
    for (int mt = 0; mt < 4; mt++)
#pragma unroll
        for (int nt = 0; nt < 2; nt++)
#pragma unroll
            for (int e2 = 0; e2 < 4; e2++) { ach[mt][nt][e2] = 0.f; acl[mt][nt][e2] = 0.f; }

#pragma unroll
    for (int mt = 0; mt < 4; mt++) {
        int mrow = mt * 16 + l16;
#pragma unroll
        for (int kq = 0; kq < 4; kq++) {
            f16x8 a = *(const f16x8*)&As[mrow * AST + kq * 32 + quad * 8];
#pragma unroll
            for (int nt = 0; nt < 2; nt++) {
                ach[mt][nt] = __builtin_amdgcn_mfma_f32_16x16x32_f16(
                    a, bhi[nt][kq], ach[mt][nt], 0, 0, 0);
                acl[mt][nt] = __builtin_amdgcn_mfma_f32_16x16x32_f16(
                    a, blo[nt][kq], acl[mt][nt], 0, 0, 0);
            }
        }
    }

    float s[2] = { 0.f, 0.f }, q[2] = { 0.f, 0.f };
#pragma unroll
    for (int mt = 0; mt < 4; mt++) {
        int rbase = r0 + mt * 16 + quad * 4;
#pragma unroll
        for (int rr = 0; rr < 4; rr++) {
            int row = rbase + rr;
            if (row < NN) {
#pragma unroll
                for (int nt = 0; nt < 2; nt++) {
                    float v = fmaf(acl[mt][nt][rr], 1.0f / 1024.0f, ach[mt][nt][rr]);
                    out[row * HD + n0w + nt * 16 + l16] = (_Float16)v;
                    s[nt] += v;
                    q[nt] = fmaf(v, v, q[nt]);
                }
            }
        }
    }
#pragma unroll
    for (int nt = 0; nt < 2; nt++) {
        float ss = s[nt], qq = q[nt];
        ss += __shfl_xor(ss, 16); ss += __shfl_xor(ss, 32);
        qq += __shfl_xor(qq, 16); qq += __shfl_xor(qq, 32);
        if (lane < 16) {
            atomicAdd(&colsum[n0w + nt * 16 + lane], ss);
            atomicAdd(&colsq[n0w + nt * 16 + lane], qq);
        }
    }
}

// ---------- pool + classifier (fp16 u, inline BN) ----------
__global__ __launch_bounds__(256) void k_pool(
    const _Float16* __restrict__ u,
    const float* __restrict__ pcolsum, const float* __restrict__ pcolsq,
    const float* __restrict__ gamma, const float* __restrict__ beta,
    const int* __restrict__ batch, const float* __restrict__ Wc,
    const float* __restrict__ bc, float* __restrict__ out) {
    __shared__ float part[2][HD];
    __shared__ float pooled[HD];
    __shared__ int range[2];
    int g = blockIdx.x;
    int tid = threadIdx.x;
    if (tid < 2) {
        int target = g + tid;
        int lo = 0, hi = NN;
        while (lo < hi) {
            int mid = (lo + hi) >> 1;
            if (batch[mid] < target) lo = mid + 1; else hi = mid;
        }
        range[tid] = lo;
    }
    __syncthreads();
    int start = range[0], end = range[1];
    int c    = tid & (HD - 1);
    int half = tid >> 7;
    float mu  = pcolsum[c] * (1.0f / NN);
    float var = pcolsq[c] * (1.0f / NN) - mu * mu;
    float sc = gamma[c] * rsqrtf(var + BN_EPS);
    float sh = beta[c] - sc * mu;
    float acc = 0.f;
    for (int n = start + half; n < end; n += 2)
        acc += fmaxf(fmaf(sc, (float)u[n * HD + c], sh), 0.f);
    part[half][c] = acc;
    __syncthreads();
    if (tid < HD) {
        float inv = 1.0f / fmaxf((float)(end - start), 1.0f);
        pooled[tid] = (part[0][tid] + part[1][tid]) * inv;
    }
    __syncthreads();
    if (tid < NC) {
        float a = bc[tid];
        for (int k = 0; k < HD; k++)
            a = fmaf(pooled[k], Wc[k * NC + tid], a);
        out[g * NC + tid] = a;
    }
}

extern "C" void kernel_launch(void* const* d_in, const int* in_sizes, int n_in,
                              void* d_out, int out_size, void* d_ws, size_t ws_size,
                              hipStream_t stream) {
    const float* x      = (const float*)d_in[0];
    const int*   ei     = (const int*)d_in[1];
    const int*   batch  = (const int*)d_in[2];
    const float* enc_W  = (const float*)d_in[3];
    const float* enc_b  = (const float*)d_in[4];
    const float* W1     = (const float*)d_in[5];
    // d_in[6] = b1, d_in[10] = b2: cancel in the following BN (mean shift)
    const float* g1     = (const float*)d_in[7];
    const float* be1    = (const float*)d_in[8];
    const float* W2     = (const float*)d_in[9];
    const float* eps_g  = (const float*)d_in[11];
    const float* bn_g   = (const float*)d_in[12];
    const float* bn_b   = (const float*)d_in[13];
    const float* cls_W  = (const float*)d_in[14];
    const float* cls_b  = (const float*)d_in[15];
    float* out = (float*)d_out;

    _Float16* Wt   = (_Float16*)d_ws;                  // 12 x HD x HD fp16 (hi:0-5, lo:6-11)
    _Float16* bufZ = Wt + 12 * HD * HD;                // NN*HD fp16 (aggr out)
    _Float16* bufT = bufZ + NN * HD;                   // NN*HD fp16 (gemm1 out)
    _Float16* bufU = bufT + NN * HD;                   // NN*HD fp16 (gathered tensor)
    float* stats  = (float*)(bufU + NN * HD);          // 6 x 256 f32
    int* counts   = (int*)(stats + 6 * 256);           // NN (also cursor)
    int* row_ptr  = counts + NN;                       // NN+1
    int* csr_src  = row_ptr + NN + 1;                  // NE

    hipMemsetAsync(stats, 0, (6 * 256 + NN) * sizeof(int), stream);

    dim3 b256(256);
    k_setup<<<3798, b256, 0, stream>>>(x, enc_W, enc_b, W1, W2, ei, Wt, bufU, counts);
    k_scan<<<1, 1024, 0, stream>>>(counts, row_ptr, counts /*cursor*/);
    k_fill<<<(NE + 255) / 256, b256, 0, stream>>>(ei, counts, csr_src);

    const int aggr_blocks = (NN * 16 + 255) / 256;   // 1250
    const int gemm_blocks = (NN + 63) / 64;          // 313

    for (int l = 0; l < NL; l++) {
        float* st1 = stats + (2 * l) * 256;       // t stats
        float* st2 = stats + (2 * l + 1) * 256;   // u stats
        _Float16* Whi1 = Wt + (2 * l) * HD * HD;
        _Float16* Wlo1 = Wt + (6 + 2 * l) * HD * HD;
        _Float16* Whi2 = Wt + (2 * l + 1) * HD * HD;
        _Float16* Wlo2 = Wt + (6 + 2 * l + 1) * HD * HD;
        if (l == 0) {
            k_aggr<false><<<aggr_blocks, b256, 0, stream>>>(
                row_ptr, csr_src, bufU, nullptr, nullptr, nullptr, nullptr,
                eps_g, l, bufZ);
        } else {
            float* stp = stats + (2 * (l - 1) + 1) * 256;
            k_aggr<true><<<aggr_blocks, b256, 0, stream>>>(
                row_ptr, csr_src, bufU, stp, stp + 128,
                bn_g + (l - 1) * HD, bn_b + (l - 1) * HD, eps_g, l, bufZ);
        }
        k_gemm<false><<<gemm_blocks, b256, 0, stream>>>(
            bufZ, Whi1, Wlo1, nullptr, nullptr, nullptr, nullptr,
            bufT, st1, st1 + 128);
        k_gemm<true><<<gemm_blocks, b256, 0, stream>>>(
            bufT, Whi2, Wlo2, st1, st1 + 128, g1 + l * HD, be1 + l * HD,
            bufU, st2, st2 + 128);
    }
    float* st5 = stats + 5 * 256;
    k_pool<<<NG, b256, 0, stream>>>(bufU, st5, st5 + 128,
                                    bn_g + 2 * HD, bn_b + 2 * HD,
                                    batch, cls_W, cls_b, out);
}

// Round 12
// 357.670 us; speedup vs baseline: 1.2183x; 1.0115x over previous
//
#include <hip/hip_runtime.h>

#define NN 20000
#define NE 640000
#define HD 128
#define NL 3
#define NG 128
#define NC 2
#define BN_EPS 1e-5f

typedef __attribute__((ext_vector_type(4))) float f32x4;
typedef __attribute__((ext_vector_type(8))) _Float16 f16x8;

// ---------- fused setup: weight fp16-split prep + p/q + dst histogram ----------
// W = Whi + Wlo/1024, both fp16. p = encW @ W1[0], q = encb @ W1[0].
// blocks [0,48): prep; 48: p/q; [49,2549): hist
__global__ void k_setup(const float* __restrict__ encW, const float* __restrict__ encb,
                        const float* __restrict__ W1, const float* __restrict__ W2,
                        const int* __restrict__ ei,
                        _Float16* __restrict__ Wt,
                        float* __restrict__ pq,          // p[128] | q[128]
                        int* __restrict__ counts) {
    int b = blockIdx.x, tid = threadIdx.x;
    if (b < 48) {
        int t = b * 256 + tid;                 // 6*2048 = 12288
        if (t >= 6 * 2048) return;
        int mat = t >> 11;
        int rem = t & 2047;
        int n  = rem >> 4;
        int k0 = (rem & 15) * 8;
        int l  = mat >> 1;
        const float* src = (mat & 1) ? (W2 + l * HD * HD) : (W1 + l * HD * HD);
        _Float16* dhi = Wt + mat * HD * HD;
        _Float16* dlo = Wt + (6 + mat) * HD * HD;
        f16x8 hi, lo;
#pragma unroll
        for (int j = 0; j < 8; j++) {
            float w = src[(k0 + j) * HD + n];
            _Float16 hh = (_Float16)w;
            hi[j] = hh;
            lo[j] = (_Float16)((w - (float)hh) * 1024.0f);
        }
        *(f16x8*)&dhi[n * HD + k0] = hi;
        *(f16x8*)&dlo[n * HD + k0] = lo;
    } else if (b == 48) {
        if (tid < HD) {
            float ps = 0.f, qs = 0.f;
            for (int k = 0; k < HD; k++) {
                float w = W1[k * HD + tid];
                ps = fmaf(encW[k], w, ps);
                qs = fmaf(encb[k], w, qs);
            }
            pq[tid] = ps;
            pq[HD + tid] = qs;
        }
    } else {
        int e = (b - 49) * 256 + tid;          // NE
        if (e >= NE) return;
        atomicAdd(&counts[ei[NE + e]], 1);
    }
}

// ---------- CSR scan ----------
__global__ __launch_bounds__(1024) void k_scan(const int* __restrict__ counts,
                                               int* __restrict__ row_ptr,
                                               int* __restrict__ cursor) {
    __shared__ int sdata[1024];
    int tid = threadIdx.x;
    int base = tid * 20;
    int loc[20];
    int run = 0;
#pragma unroll
    for (int j = 0; j < 20; j++) {
        int i = base + j;
        int v = (i < NN) ? counts[i] : 0;
        loc[j] = run;
        run += v;
    }
    sdata[tid] = run;
    __syncthreads();
    for (int off = 1; off < 1024; off <<= 1) {
        int t = (tid >= off) ? sdata[tid - off] : 0;
        __syncthreads();
        sdata[tid] += t;
        __syncthreads();
    }
    int excl = sdata[tid] - run;
#pragma unroll
    for (int j = 0; j < 20; j++) {
        int i = base + j;
        if (i < NN) {
            int o = excl + loc[j];
            row_ptr[i] = o;
            cursor[i]  = o;
        }
    }
    if (tid == 1023) row_ptr[NN] = NE;
}

__global__ void k_fill(const int* __restrict__ ei, int* __restrict__ cursor,
                       int* __restrict__ csr_src) {
    int e = blockIdx.x * blockDim.x + threadIdx.x;
    if (e >= NE) return;
    int pos = atomicAdd(&cursor[ei[NE + e]], 1);
    csr_src[pos] = ei[e];
}

// ---------- layer-0 scalar aggregation ----------
// a[n] = (1+eps0)*x[n] + sum_s x[s];  d[n] = (1+eps0) + deg[n]
// + reductions Sa, Sd, Saa, Sdd, Sad into scal[5] (for analytic BN of t0).
__global__ void k_deg(const int* __restrict__ row_ptr, const int* __restrict__ csr_src,
                      const float* __restrict__ x, const float* __restrict__ eps_gin,
                      float* __restrict__ av, float* __restrict__ dv,
                      float* __restrict__ scal) {
    int n = blockIdx.x * blockDim.x + threadIdx.x;
    float a = 0.f, d = 0.f;
    if (n < NN) {
        float e = 1.0f + eps_gin[0];
        int p = row_ptr[n], end = row_ptr[n + 1];
        float S = 0.f;
        for (; p + 3 < end; p += 4) {
            float s0 = x[csr_src[p]], s1 = x[csr_src[p + 1]];
            float s2 = x[csr_src[p + 2]], s3 = x[csr_src[p + 3]];
            S += (s0 + s1) + (s2 + s3);
        }
        for (; p < end; p++) S += x[csr_src[p]];
        a = fmaf(e, x[n], S);
        d = e + (float)(end - row_ptr[n]);
        av[n] = a;
        dv[n] = d;
    }
    float v[5] = { a, d, a * a, d * d, a * d };
#pragma unroll
    for (int j = 0; j < 5; j++) {
        float t = v[j];
        t += __shfl_xor(t, 1);  t += __shfl_xor(t, 2);  t += __shfl_xor(t, 4);
        t += __shfl_xor(t, 8);  t += __shfl_xor(t, 16); t += __shfl_xor(t, 32);
        v[j] = t;
    }
    if ((threadIdx.x & 63) == 0)
#pragma unroll
        for (int j = 0; j < 5; j++) atomicAdd(&scal[j], v[j]);
}

// ---------- layer-0 GEMM2: rank-2 A (a*p + d*q), analytic BN, fp16 MFMA ----------
#define AST 136
__global__ __launch_bounds__(256) void k_gemmA(
    const float* __restrict__ av, const float* __restrict__ dv,
    const float* __restrict__ pq, const float* __restrict__ scal,
    const float* __restrict__ gamma, const float* __restrict__ beta,
    const _Float16* __restrict__ Whi, const _Float16* __restrict__ Wlo,
    _Float16* __restrict__ out,
    float* __restrict__ colsum, float* __restrict__ colsq) {
    __shared__ __align__(16) _Float16 As[64 * AST];
    int tid  = threadIdx.x;
    int wave = tid >> 6, lane = tid & 63;
    int quad = lane >> 4, l16 = lane & 15;
    int r0   = blockIdx.x * 64;
    int n0w  = wave * 32;

    f16x8 bhi[2][4], blo[2][4];
#pragma unroll
    for (int nt = 0; nt < 2; nt++) {
        int n = n0w + nt * 16 + l16;
#pragma unroll
        for (int kq = 0; kq < 4; kq++) {
            int k = kq * 32 + quad * 8;
            bhi[nt][kq] = *(const f16x8*)&Whi[n * HD + k];
            blo[nt][kq] = *(const f16x8*)&Wlo[n * HD + k];
        }
    }

    // stage: t0 = a*p + d*q, BN from 5 scalars, ReLU, fp16
    {
        int c8 = (tid & 15) * 8;
        int nl = tid >> 4;
        float Sa = scal[0], Sd = scal[1], Saa = scal[2], Sdd = scal[3], Sad = scal[4];
        float pj[8], qj[8], sc[8], sh[8];
#pragma unroll
        for (int j = 0; j < 8; j++) {
            float P = pq[c8 + j], Q = pq[HD + c8 + j];
            pj[j] = P; qj[j] = Q;
            float mu  = (Sa * P + Sd * Q) * (1.0f / NN);
            float ex2 = (Saa * P * P + 2.f * Sad * P * Q + Sdd * Q * Q) * (1.0f / NN);
            float var = ex2 - mu * mu;
            float g = gamma[c8 + j] * rsqrtf(var + BN_EPS);
            sc[j] = g;
            sh[j] = beta[c8 + j] - g * mu;
        }
#pragma unroll
        for (int i = 0; i < 4; i++) {
            int r = i * 16 + nl;
            int row = r0 + r;
            f16x8 o = (f16x8)(_Float16)0.f;
            if (row < NN) {
                float a = av[row], d = dv[row];
#pragma unroll
                for (int j = 0; j < 8; j++) {
                    float t0 = fmaf(a, pj[j], d * qj[j]);
                    o[j] = (_Float16)fmaxf(fmaf(sc[j], t0, sh[j]), 0.f);
                }
            }
            *(f16x8*)&As[r * AST + c8] = o;
        }
    }
    __syncthreads();

    f32x4 ach[4][2], acl[4][2];
#pragma unroll
    for (int mt = 0; mt < 4; mt++)
#pragma unroll
        for (int nt = 0; nt < 2; nt++)
#pragma unroll
            for (int e2 = 0; e2 < 4; e2++) { ach[mt][nt][e2] = 0.f; acl[mt][nt][e2] = 0.f; }

#pragma unroll
    for (int mt = 0; mt < 4; mt++) {
        int mrow = mt * 16 + l16;
#pragma unroll
        for (int kq = 0; kq < 4; kq++) {
            f16x8 a = *(const f16x8*)&As[mrow * AST + kq * 32 + quad * 8];
#pragma unroll
            for (int nt = 0; nt < 2; nt++) {
                ach[mt][nt] = __builtin_amdgcn_mfma_f32_16x16x32_f16(
                    a, bhi[nt][kq], ach[mt][nt], 0, 0, 0);
                acl[mt][nt] = __builtin_amdgcn_mfma_f32_16x16x32_f16(
                    a, blo[nt][kq], acl[mt][nt], 0, 0, 0);
            }
        }
    }

    float s[2] = { 0.f, 0.f }, q[2] = { 0.f, 0.f };
#pragma unroll
    for (int mt = 0; mt < 4; mt++) {
        int rbase = r0 + mt * 16 + quad * 4;
#pragma unroll
        for (int rr = 0; rr < 4; rr++) {
            int row = rbase + rr;
            if (row < NN) {
#pragma unroll
                for (int nt = 0; nt < 2; nt++) {
                    float v = fmaf(acl[mt][nt][rr], 1.0f / 1024.0f, ach[mt][nt][rr]);
                    out[row * HD + n0w + nt * 16 + l16] = (_Float16)v;
                    s[nt] += v;
                    q[nt] = fmaf(v, v, q[nt]);
                }
            }
        }
    }
#pragma unroll
    for (int nt = 0; nt < 2; nt++) {
        float ss = s[nt], qq = q[nt];
        ss += __shfl_xor(ss, 16); ss += __shfl_xor(ss, 32);
        qq += __shfl_xor(qq, 16); qq += __shfl_xor(qq, 32);
        if (lane < 16) {
            atomicAdd(&colsum[n0w + nt * 16 + lane], ss);
            atomicAdd(&colsq[n0w + nt * 16 + lane], qq);
        }
    }
}

// ---------- aggregation: fp16 gather, fp32 accumulate, fp16 out ----------
template <bool APPLY>
__global__ void k_aggr(const int* __restrict__ row_ptr, const int* __restrict__ csr_src,
                       const _Float16* __restrict__ u,
                       const float* __restrict__ pcolsum, const float* __restrict__ pcolsq,
                       const float* __restrict__ gamma, const float* __restrict__ beta,
                       const float* __restrict__ eps_gin, int l,
                       _Float16* __restrict__ z) {
    int i = blockIdx.x * blockDim.x + threadIdx.x;   // NN*16
    if (i >= NN * 16) return;
    int n  = i >> 4;
    int c8 = (i & 15) * 8;
    float e = 1.0f + eps_gin[l];
    float sc[8], sh[8];
    if (APPLY) {
#pragma unroll
        for (int j = 0; j < 8; j++) {
            float mu  = pcolsum[c8 + j] * (1.0f / NN);
            float var = pcolsq[c8 + j] * (1.0f / NN) - mu * mu;
            float a = gamma[c8 + j] * rsqrtf(var + BN_EPS);
            sc[j] = a;
            sh[j] = beta[c8 + j] - a * mu;
        }
    }
    float acc[8];
    {
        f16x8 r = *(const f16x8*)&u[n * HD + c8];
#pragma unroll
        for (int j = 0; j < 8; j++) {
            float v = (float)r[j];
            if (APPLY) v = fmaxf(fmaf(sc[j], v, sh[j]), 0.f);
            acc[j] = e * v;
        }
    }
    int p = row_ptr[n], end = row_ptr[n + 1];
    for (; p + 7 < end; p += 8) {
        f16x8 r[8];
#pragma unroll
        for (int j = 0; j < 8; j++) r[j] = *(const f16x8*)&u[csr_src[p + j] * HD + c8];
#pragma unroll
        for (int j = 0; j < 8; j++)
#pragma unroll
            for (int q = 0; q < 8; q++) {
                float v = (float)r[j][q];
                if (APPLY) v = fmaxf(fmaf(sc[q], v, sh[q]), 0.f);
                acc[q] += v;
            }
    }
    for (; p < end; p++) {
        f16x8 r = *(const f16x8*)&u[csr_src[p] * HD + c8];
#pragma unroll
        for (int q = 0; q < 8; q++) {
            float v = (float)r[q];
            if (APPLY) v = fmaxf(fmaf(sc[q], v, sh[q]), 0.f);
            acc[q] += v;
        }
    }
    f16x8 o;
#pragma unroll
    for (int j = 0; j < 8; j++) o[j] = (_Float16)acc[j];
    *(f16x8*)&z[n * HD + c8] = o;
}

// ---------- fp16-MFMA GEMM with scaled weight split, LDS-staged A ----------
template <bool BNRELU>
__global__ __launch_bounds__(256) void k_gemm(
    const _Float16* __restrict__ A,
    const _Float16* __restrict__ Whi, const _Float16* __restrict__ Wlo,
    const float* __restrict__ pcolsum, const float* __restrict__ pcolsq,
    const float* __restrict__ gamma, const float* __restrict__ beta,
    _Float16* __restrict__ out,
    float* __restrict__ colsum, float* __restrict__ colsq) {
    __shared__ __align__(16) _Float16 As[64 * AST];
    int tid  = threadIdx.x;
    int wave = tid >> 6, lane = tid & 63;
    int quad = lane >> 4, l16 = lane & 15;
    int r0   = blockIdx.x * 64;
    int n0w  = wave * 32;

    f16x8 bhi[2][4], blo[2][4];
#pragma unroll
    for (int nt = 0; nt < 2; nt++) {
        int n = n0w + nt * 16 + l16;
#pragma unroll
        for (int kq = 0; kq < 4; kq++) {
            int k = kq * 32 + quad * 8;
            bhi[nt][kq] = *(const f16x8*)&Whi[n * HD + k];
            blo[nt][kq] = *(const f16x8*)&Wlo[n * HD + k];
        }
    }

    {
        int c8 = (tid & 15) * 8;
        int nl = tid >> 4;
        float sc[8], sh[8];
        if (BNRELU) {
#pragma unroll
            for (int j = 0; j < 8; j++) {
                float mu  = pcolsum[c8 + j] * (1.0f / NN);
                float var = pcolsq[c8 + j] * (1.0f / NN) - mu * mu;
                float a = gamma[c8 + j] * rsqrtf(var + BN_EPS);
                sc[j] = a;
                sh[j] = beta[c8 + j] - a * mu;
            }
        }
#pragma unroll
        for (int i = 0; i < 4; i++) {
            int r = i * 16 + nl;
            int row = r0 + r;
            f16x8 o = (f16x8)(_Float16)0.f;
            if (row < NN) {
                f16x8 v = *(const f16x8*)&A[row * HD + c8];
                if (BNRELU) {
#pragma unroll
                    for (int j = 0; j < 8; j++)
                        o[j] = (_Float16)fmaxf(fmaf(sc[j], (float)v[j], sh[j]), 0.f);
                } else {
                    o = v;
                }
            }
            *(f16x8*)&As[r * AST + c8] = o;
        }
    }
    __syncthreads();

    f32x4 ach[4][2], acl[4][2];
#pragma unroll
    for (int mt = 0; mt < 4; mt++)
#pragma unroll
        for (int nt = 0; nt < 2; nt++)
#pragma unroll
            for (int e2 = 0; e2 < 4; e2++) { ach[mt][nt][e2] = 0.f; acl[mt][nt][e2] = 0.f; }

#pragma unroll
    for (int mt = 0; mt < 4; mt++) {
        int mrow = mt * 16 + l16;
#pragma unroll
        for (int kq = 0; kq < 4; kq++) {
            f16x8 a = *(const f16x8*)&As[mrow * AST + kq * 32 + quad * 8];
#pragma unroll
            for (int nt = 0; nt < 2; nt++) {
                ach[mt][nt] = __builtin_amdgcn_mfma_f32_16x16x32_f16(
                    a, bhi[nt][kq], ach[mt][nt], 0, 0, 0);
                acl[mt][nt] = __builtin_amdgcn_mfma_f32_16x16x32_f16(
                    a, blo[nt][kq], acl[mt][nt], 0, 0, 0);
            }
        }
    }

    float s[2] = { 0.f, 0.f }, q[2] = { 0.f, 0.f };
#pragma unroll
    for (int mt = 0; mt < 4; mt++) {
        int rbase = r0 + mt * 16 + quad * 4;
#pragma unroll
        for (int rr = 0; rr < 4; rr++) {
            int row = rbase + rr;
            if (row < NN) {
#pragma unroll
                for (int nt = 0; nt < 2; nt++) {
                    float v = fmaf(acl[mt][nt][rr], 1.0f / 1024.0f, ach[mt][nt][rr]);
                    out[row * HD + n0w + nt * 16 + l16] = (_Float16)v;
                    s[nt] += v;
                    q[nt] = fmaf(v, v, q[nt]);
                }
            }
        }
    }
#pragma unroll
    for (int nt = 0; nt < 2; nt++) {
        float ss = s[nt], qq = q[nt];
        ss += __shfl_xor(ss, 16); ss += __shfl_xor(ss, 32);
        qq += __shfl_xor(qq, 16); qq += __shfl_xor(qq, 32);
        if (lane < 16) {
            atomicAdd(&colsum[n0w + nt * 16 + lane], ss);
            atomicAdd(&colsq[n0w + nt * 16 + lane], qq);
        }
    }
}

// ---------- pool + classifier (fp16 u, inline BN) ----------
__global__ __launch_bounds__(256) void k_pool(
    const _Float16* __restrict__ u,
    const float* __restrict__ pcolsum, const float* __restrict__ pcolsq,
    const float* __restrict__ gamma, const float* __restrict__ beta,
    const int* __restrict__ batch, const float* __restrict__ Wc,
    const float* __restrict__ bc, float* __restrict__ out) {
    __shared__ float part[2][HD];
    __shared__ float pooled[HD];
    __shared__ int range[2];
    int g = blockIdx.x;
    int tid = threadIdx.x;
    if (tid < 2) {
        int target = g + tid;
        int lo = 0, hi = NN;
        while (lo < hi) {
            int mid = (lo + hi) >> 1;
            if (batch[mid] < target) lo = mid + 1; else hi = mid;
        }
        range[tid] = lo;
    }
    __syncthreads();
    int start = range[0], end = range[1];
    int c    = tid & (HD - 1);
    int half = tid >> 7;
    float mu  = pcolsum[c] * (1.0f / NN);
    float var = pcolsq[c] * (1.0f / NN) - mu * mu;
    float sc = gamma[c] * rsqrtf(var + BN_EPS);
    float sh = beta[c] - sc * mu;
    float acc = 0.f;
    for (int n = start + half; n < end; n += 2)
        acc += fmaxf(fmaf(sc, (float)u[n * HD + c], sh), 0.f);
    part[half][c] = acc;
    __syncthreads();
    if (tid < HD) {
        float inv = 1.0f / fmaxf((float)(end - start), 1.0f);
        pooled[tid] = (part[0][tid] + part[1][tid]) * inv;
    }
    __syncthreads();
    if (tid < NC) {
        float a = bc[tid];
        for (int k = 0; k < HD; k++)
            a = fmaf(pooled[k], Wc[k * NC + tid], a);
        out[g * NC + tid] = a;
    }
}

extern "C" void kernel_launch(void* const* d_in, const int* in_sizes, int n_in,
                              void* d_out, int out_size, void* d_ws, size_t ws_size,
                              hipStream_t stream) {
    const float* x      = (const float*)d_in[0];
    const int*   ei     = (const int*)d_in[1];
    const int*   batch  = (const int*)d_in[2];
    const float* enc_W  = (const float*)d_in[3];
    const float* enc_b  = (const float*)d_in[4];
    const float* W1     = (const float*)d_in[5];
    // d_in[6] = b1, d_in[10] = b2: cancel in the following BN (mean shift)
    const float* g1     = (const float*)d_in[7];
    const float* be1    = (const float*)d_in[8];
    const float* W2     = (const float*)d_in[9];
    const float* eps_g  = (const float*)d_in[11];
    const float* bn_g   = (const float*)d_in[12];
    const float* bn_b   = (const float*)d_in[13];
    const float* cls_W  = (const float*)d_in[14];
    const float* cls_b  = (const float*)d_in[15];
    float* out = (float*)d_out;

    _Float16* Wt   = (_Float16*)d_ws;                  // 12 x HD x HD fp16 (hi:0-5, lo:6-11)
    _Float16* bufZ = Wt + 12 * HD * HD;                // NN*HD fp16 (aggr out)
    _Float16* bufT = bufZ + NN * HD;                   // NN*HD fp16 (gemm1 out)
    _Float16* bufU = bufT + NN * HD;                   // NN*HD fp16 (gathered tensor)
    float* pq     = (float*)(bufU + NN * HD);          // 2*HD (p|q)
    float* av     = pq + 2 * HD;                       // NN
    float* dv     = av + NN;                           // NN
    float* stats  = dv + NN;                           // 6 x 256 f32 (unit0 unused)
    float* scal   = stats + 6 * 256;                   // 8 (Sa,Sd,Saa,Sdd,Sad)
    int* counts   = (int*)(scal + 8);                  // NN (also cursor)
    int* row_ptr  = counts + NN;                       // NN+1
    int* csr_src  = row_ptr + NN + 1;                  // NE

    // stats + scal + counts contiguous: one memset
    hipMemsetAsync(stats, 0, (6 * 256 + 8 + NN) * sizeof(int), stream);

    dim3 b256(256);
    k_setup<<<2549, b256, 0, stream>>>(enc_W, enc_b, W1, W2, ei, Wt, pq, counts);
    k_scan<<<1, 1024, 0, stream>>>(counts, row_ptr, counts /*cursor*/);
    k_fill<<<(NE + 255) / 256, b256, 0, stream>>>(ei, counts, csr_src);
    k_deg<<<(NN + 255) / 256, b256, 0, stream>>>(row_ptr, csr_src, x, eps_g, av, dv, scal);

    const int aggr_blocks = (NN * 16 + 255) / 256;   // 1250
    const int gemm_blocks = (NN + 63) / 64;          // 313

    // ---- layer 0: rank-2 collapse (no enc, no aggr, no gemm1) ----
    float* st2_0 = stats + 1 * 256;
    k_gemmA<<<gemm_blocks, b256, 0, stream>>>(
        av, dv, pq, scal, g1, be1,
        Wt + 1 * HD * HD, Wt + 7 * HD * HD, bufU, st2_0, st2_0 + 128);

    // ---- layers 1,2 ----
    for (int l = 1; l < NL; l++) {
        float* st1 = stats + (2 * l) * 256;       // t stats
        float* st2 = stats + (2 * l + 1) * 256;   // u stats
        float* stp = stats + (2 * (l - 1) + 1) * 256;
        _Float16* Whi1 = Wt + (2 * l) * HD * HD;
        _Float16* Wlo1 = Wt + (6 + 2 * l) * HD * HD;
        _Float16* Whi2 = Wt + (2 * l + 1) * HD * HD;
        _Float16* Wlo2 = Wt + (6 + 2 * l + 1) * HD * HD;
        k_aggr<true><<<aggr_blocks, b256, 0, stream>>>(
            row_ptr, csr_src, bufU, stp, stp + 128,
            bn_g + (l - 1) * HD, bn_b + (l - 1) * HD, eps_g, l, bufZ);
        k_gemm<false><<<gemm_blocks, b256, 0, stream>>>(
            bufZ, Whi1, Wlo1, nullptr, nullptr, nullptr, nullptr,
            bufT, st1, st1 + 128);
        k_gemm<true><<<gemm_blocks, b256, 0, stream>>>(
            bufT, Whi2, Wlo2, st1, st1 + 128, g1 + l * HD, be1 + l * HD,
            bufU, st2, st2 + 128);
    }
    float* st5 = stats + 5 * 256;
    k_pool<<<NG, b256, 0, stream>>>(bufU, st5, st5 + 128,
                                    bn_g + 2 * HD, bn_b + 2 * HD,
                                    batch, cls_W, cls_b, out);
}